// Round 7
// baseline (632.724 us; speedup 1.0000x reference)
//
#include <hip/hip_runtime.h>
#include <hip/hip_bf16.h>
#include <math.h>

typedef unsigned short ushort;
typedef __attribute__((ext_vector_type(8))) short short8;
typedef __attribute__((ext_vector_type(8))) unsigned short ushort8;
typedef __attribute__((ext_vector_type(4))) unsigned short ushort4v;
typedef __attribute__((ext_vector_type(4))) float f32x4;

__device__ __forceinline__ ushort f2bb(float v) {
    return __builtin_bit_cast(ushort, __float2bfloat16(v));
}
__device__ __forceinline__ float bf2f(ushort u) {
    return __bfloat162float(__builtin_bit_cast(__hip_bfloat16, u));
}
// async global->LDS 16B/lane; LDS dest = wave-uniform base + lane*16
__device__ __forceinline__ void gl2lds16(const ushort* g, ushort* l) {
    __builtin_amdgcn_global_load_lds(
        (const __attribute__((address_space(1))) unsigned int*)g,
        (__attribute__((address_space(3))) unsigned int*)l, 16, 0, 0);
}

// ---------------------------------------------------------------------------
// B=32, C=512, H=W=32, NH=8, dh=64, N=256 pooled, hidden=2048.
// r7 (MLP fused v2): r6 hit the MFMA floor (MfmaUtil*dur == 56us) but stalled
// 83%: 1 blk/CU (96KB LDS), 12.6M LDS-conflict cycles from scalar 2B Hsm
// writes, per-kh W-frag latency. Fixes:
//  * GEMM1 operands SWAPPED -> C^T: lane holds 4 consecutive h at fixed m ->
//    Hsm pack is one 8B ushort4 store (4/thread/hb, ~2-way banks, free).
//  * Hsm 32->16KB (hidden chunk 128, 16 hb iters) -> LDS 80KB -> 2 blk/CU,
//    4 waves/SIMD; __launch_bounds__(512,4) caps VGPR 128 (acc now 80).
//  * b1 bias hoisted to one float4 per hb.
// r4 (kept): attn on MFMA, V stored transposed by QKV epilogue.
// r3 (kept): 128^2 dbuf GEMM for QKV/proj/convT.
// r2 (kept): chunk-XOR LDS swizzle, full-line epilogue stores, XCD swizzle.
// ---------------------------------------------------------------------------

__global__ __launch_bounds__(256) void cvtw_k(const float* __restrict__ in,
                                              ushort* __restrict__ out, int n4) {
    int i = blockIdx.x * 256 + threadIdx.x;
    if (i >= n4) return;
    float4 v = ((const float4*)in)[i];
    ushort4v o;
    o.x = f2bb(v.x); o.y = f2bb(v.y); o.z = f2bb(v.z); o.w = f2bb(v.w);
    ((ushort4v*)out)[i] = o;
}

// ct_w [512][2048] fp32 -> [2048][512] bf16
__global__ __launch_bounds__(256) void cvtt_k(const float* __restrict__ in,
                                              ushort* __restrict__ out) {
    __shared__ float tl[32][33];
    int c0 = blockIdx.y * 32, j0 = blockIdx.x * 32;
    int tr = threadIdx.x >> 5, tc = threadIdx.x & 31;
#pragma unroll
    for (int p4 = 0; p4 < 4; ++p4)
        tl[tr + p4 * 8][tc] = in[(size_t)(c0 + tr + p4 * 8) * 2048 + j0 + tc];
    __syncthreads();
#pragma unroll
    for (int p4 = 0; p4 < 4; ++p4)
        out[(size_t)(j0 + tr + p4 * 8) * 512 + c0 + tc] = f2bb(tl[tc][tr + p4 * 8]);
}

// K1: depthwise 3x3 + bias + residual + 2x2 avgpool -> xp bf16 [B,C,16,16]
__global__ __launch_bounds__(256) void dwpool_k(const float* __restrict__ x,
                                                const float* __restrict__ dww,
                                                const float* __restrict__ dwb,
                                                ushort* __restrict__ xp) {
    int bc = blockIdx.x;
    int c = bc & 511;
    __shared__ float tile[32][33];
    __shared__ float w9[9];
    const float* xb = x + (size_t)bc * 1024;
    int tid = threadIdx.x;
    for (int i = tid; i < 1024; i += 256) tile[i >> 5][i & 31] = xb[i];
    if (tid < 9) w9[tid] = dww[c * 9 + tid];
    __syncthreads();
    float bv = dwb[c];
    int ph = tid >> 4, pw = tid & 15;
    float s = 0.f;
#pragma unroll
    for (int dy = 0; dy < 2; ++dy) {
#pragma unroll
        for (int dx = 0; dx < 2; ++dx) {
            int hh = 2 * ph + dy, ww = 2 * pw + dx;
            float a = bv + tile[hh][ww];
#pragma unroll
            for (int ky = 0; ky < 3; ++ky) {
                int yy = hh + ky - 1;
                if (yy < 0 || yy > 31) continue;
#pragma unroll
                for (int kx = 0; kx < 3; ++kx) {
                    int xx = ww + kx - 1;
                    if (xx < 0 || xx > 31) continue;
                    a += w9[ky * 3 + kx] * tile[yy][xx];
                }
            }
            s += a;
        }
    }
    xp[(size_t)bc * 256 + tid] = f2bb(0.25f * s);
}

// K2: LN1 stats per token over C=512; xp bf16 [b][c][n]
__global__ __launch_bounds__(256) void ln1_stats_k(const ushort* __restrict__ xp,
                                                   float* __restrict__ m1,
                                                   float* __restrict__ r1) {
    __shared__ float sh_s[4][64], sh_q[4][64];
    int blk = blockIdx.x;
    int b = blk >> 2;
    int n0 = (blk & 3) * 64;
    int t = threadIdx.x & 63, w = threadIdx.x >> 6;
    float s = 0.f, ss = 0.f;
    for (int i = 0; i < 128; ++i) {
        int c = w * 128 + i;
        float v = bf2f(xp[(size_t)(b * 512 + c) * 256 + n0 + t]);
        s += v; ss += v * v;
    }
    sh_s[w][t] = s; sh_q[w][t] = ss;
    __syncthreads();
    if (w == 0) {
        s  = sh_s[0][t] + sh_s[1][t] + sh_s[2][t] + sh_s[3][t];
        ss = sh_q[0][t] + sh_q[1][t] + sh_q[2][t] + sh_q[3][t];
        float m = s * (1.0f / 512.0f);
        m1[b * 256 + n0 + t] = m;
        r1[b * 256 + n0 + t] = rsqrtf(ss * (1.0f / 512.0f) - m * m + 1e-6f);
    }
}

// K3: LN1 apply + transpose: xp [b][c][n] -> a_ln [m][c] bf16 normalized
__global__ __launch_bounds__(256) void ln1_apply_k(const ushort* __restrict__ xp,
                                                   const float* __restrict__ m1,
                                                   const float* __restrict__ r1,
                                                   const float* __restrict__ g,
                                                   const float* __restrict__ beta,
                                                   ushort* __restrict__ a_ln) {
    __shared__ float tl[64][66];
    int blk = blockIdx.x;                 // b*32 + ct*4 + nt
    int b = blk >> 5, ct = (blk >> 2) & 7, nt = blk & 3;
    int t = threadIdx.x;
    int rq = t >> 6, nl = t & 63;
#pragma unroll
    for (int i = 0; i < 16; ++i) {
        int r = rq * 16 + i;
        int c = ct * 64 + r;
        tl[r][nl] = bf2f(xp[(size_t)(b * 512 + c) * 256 + nt * 64 + nl]);
    }
    __syncthreads();
    int r2 = t >> 2, cq = t & 3;
    int m = b * 256 + nt * 64 + r2;
    float mu = m1[m], rs = r1[m];
#pragma unroll
    for (int hh = 0; hh < 2; ++hh) {
        ushort8 o;
#pragma unroll
        for (int j = 0; j < 8; ++j) {
            int cl = cq * 16 + hh * 8 + j;
            int c = ct * 64 + cl;
            o[j] = f2bb((tl[cl][r2] - mu) * rs * g[c] + beta[c]);
        }
        *(ushort8*)&a_ln[(size_t)m * 512 + ct * 64 + cq * 16 + hh * 8] = o;
    }
}

// K7: LN2 fused stats+normalize, in place. y0 rows split across yB / yT.
__global__ __launch_bounds__(256) void ln2_fuse_k(ushort* __restrict__ yB,
                                                  ushort* __restrict__ yT,
                                                  const float* __restrict__ g,
                                                  const float* __restrict__ beta) {
    int w = threadIdx.x >> 6, lane = threadIdx.x & 63;
    int row = blockIdx.x * 4 + w;
    ushort* base = (row < 8192) ? (yB + (size_t)row * 512)
                                : (yT + (size_t)(row - 8192) * 512);
    ushort8 raw = *(ushort8*)&base[lane * 8];
    float v[8];
    float s = 0.f, ss = 0.f;
#pragma unroll
    for (int j = 0; j < 8; ++j) { v[j] = bf2f(raw[j]); s += v[j]; ss += v[j] * v[j]; }
#pragma unroll
    for (int off = 1; off < 64; off <<= 1) { s += __shfl_xor(s, off); ss += __shfl_xor(ss, off); }
    float mu = s * (1.0f / 512.0f);
    float rs = rsqrtf(ss * (1.0f / 512.0f) - mu * mu + 1e-6f);
    ushort8 o;
#pragma unroll
    for (int j = 0; j < 8; ++j) {
        int c = lane * 8 + j;
        o[j] = f2bb((v[j] - mu) * rs * g[c] + beta[c]);
    }
    *(ushort8*)&base[lane * 8] = o;
}

// ---------------------------------------------------------------------------
// MFMA GEMM (128xBN, BK=32, dbuf): out[m,j] = sum_k A[m,k]*W[j,k].
// MODE 0 QKV : out bf16 q/k [sect][bh][64 d][256 n]; V TRANSPOSED [bh][n][d]
// MODE 1 PROJ: out bf16 t2 = 2*(acc+bias), row-major LD=512
// MODE 2 CONVT: bf16 channels-last y0 (split base) + ct_b, 64B/pixel chunks
// ---------------------------------------------------------------------------
struct GP {
    const ushort* A;
    const ushort* W;
    const float* bias;
    ushort* outB;
    ushort* outB2;
    float* outF;
    const float* inp;
    int K, m0;
};

template <int MODE, int BN>
__global__ __launch_bounds__(256) void mgemm_k(GP p) {
    constexpr int MT = (BN == 128) ? 4 : 2;   // 16-row m-tiles per wave
    constexpr int NT = 4;                     // 16-col n-tiles per wave
    constexpr int ATILE = 128 * 32;           // ushorts per A K-tile
    constexpr int BTILE = BN * 32;            // ushorts per B K-tile
    constexpr int SMEM_US = 2 * (ATILE + BTILE);  // dbuf; >= all epilogue needs
    __shared__ __align__(16) ushort smem[SMEM_US];
    int tid = threadIdx.x;
    int lane = tid & 63, w = tid >> 6;
    int lr = lane & 15, lq = lane >> 4;
    int mwoff = (BN == 128) ? (w >> 1) * 64 : w * 32;
    int nwoff = (BN == 128) ? (w & 1) * 64 : 0;
    // ---- XCD-band swizzle (bijective: nwg % 8 == 0 for all grids) ----
    int gx = gridDim.x;
    int wgid = blockIdx.y * gx + blockIdx.x;
    int cpx = (gx * gridDim.y) >> 3;          // blocks per XCD
    int swz = (wgid & 7) * cpx + (wgid >> 3);
    int bx = swz % gx, by = swz / gx;
    int mbase = by * 128, nbase = bx * BN;
    // staging: 16 rows x 4 chunks; source chunk permuted so linear LDS dest
    // holds the swizzled layout (rule #21)
    int lsub = lane >> 2;
    int cchunk = (lane & 3) ^ ((lsub >> 1) & 3);
    int lcol = cchunk * 8;
    int physc = lq ^ ((lr >> 1) & 3);         // frag-read phys chunk
    f32x4 acc[MT][NT] = {};

    auto stage = [&](int buf, int kb) {
        ushort* Ab = smem + buf * ATILE;
        ushort* Bb = smem + 2 * ATILE + buf * BTILE;
#pragma unroll
        for (int i = 0; i < 2; ++i) {
            int row = w * 32 + i * 16;
            gl2lds16(p.A + (size_t)(mbase + row + lsub) * p.K + kb + lcol,
                     &Ab[row * 32]);
        }
        if constexpr (BN == 128) {
#pragma unroll
            for (int i = 0; i < 2; ++i) {
                int row = w * 32 + i * 16;
                gl2lds16(p.W + (size_t)(nbase + row + lsub) * p.K + kb + lcol,
                         &Bb[row * 32]);
            }
        } else {
            int row = w * 16;
            gl2lds16(p.W + (size_t)(nbase + row + lsub) * p.K + kb + lcol,
                     &Bb[row * 32]);
        }
    };

    // prologue: stage tile 0, wait (implicit vmcnt(0) in syncthreads)
    stage(0, 0);
    __syncthreads();
    int nk = p.K >> 5;
    for (int t = 0; t < nk; ++t) {
        int cur = t & 1;
        if (t + 1 < nk) stage(cur ^ 1, (t + 1) << 5);   // prefetch next tile
        const ushort* Ac = smem + cur * ATILE;
        const ushort* Bc = smem + 2 * ATILE + cur * BTILE;
        short8 af[MT], bfr[NT];
#pragma unroll
        for (int tt = 0; tt < MT; ++tt)
            af[tt] = *(const short8*)&Ac[(mwoff + tt * 16 + lr) * 32 + physc * 8];
#pragma unroll
        for (int tt = 0; tt < NT; ++tt)
            bfr[tt] = *(const short8*)&Bc[(nwoff + tt * 16 + lr) * 32 + physc * 8];
#pragma unroll
        for (int i = 0; i < MT; ++i)
#pragma unroll
            for (int j = 0; j < NT; ++j)
                acc[i][j] = __builtin_amdgcn_mfma_f32_16x16x32_bf16(af[i], bfr[j], acc[i][j], 0, 0, 0);
        __syncthreads();   // drains vmcnt(0): next buffer ready for all waves
    }

    // ================= epilogues (LDS restage -> vector stores) =============
    if constexpr (MODE == 1 || MODE == 3) {
        // row-major bf16 out, cols fast. eb [128][64] us, chunk^(row&7) swizzle.
        const size_t LD = (MODE == 1) ? 512 : 2048;
        ushort* eb = (ushort*)smem;
#pragma unroll
        for (int h = 0; h < 2; ++h) {
            __syncthreads();
            if ((w & 1) == h) {
#pragma unroll
                for (int ti = 0; ti < MT; ++ti)
#pragma unroll
                    for (int tj = 0; tj < NT; ++tj)
#pragma unroll
                        for (int r = 0; r < 4; ++r) {
                            int row = mwoff + ti * 16 + lq * 4 + r;     // 0..127
                            int colh = tj * 16 + lr;                    // 0..63
                            float v = acc[ti][tj][r] + p.bias[nbase + h * 64 + colh];
                            if constexpr (MODE == 1) v *= 2.0f;
                            else v = 0.5f * v * (1.0f + erff(v * 0.70710678118654752f));
                            int ph = (colh >> 3) ^ (row & 7);
                            eb[row * 64 + ph * 8 + (colh & 7)] = f2bb(v);
                        }
            }
            __syncthreads();
#pragma unroll
            for (int i = 0; i < 4; ++i) {
                int row = i * 32 + (tid >> 3);
                int ch = tid & 7;
                int pch = ch ^ (row & 7);
                short8 d = *(short8*)&eb[row * 64 + pch * 8];
                *(short8*)&p.outB[(size_t)(mbase + row) * LD + nbase + h * 64 + ch * 8] = d;
            }
        }
    } else if constexpr (MODE == 0) {
        // QKV out. eb [32 c][136 row-us] per pc chunk.
        // Q/K (cg<1024): [sect][bh][d][n], n-fast stores.
        // V  (cg>=1024): TRANSPOSED [bh][n][d], d-fast stores.
        ushort* eb = (ushort*)smem;
        int b = mbase >> 8, n0 = mbase & 255;
#pragma unroll
        for (int pc = 0; pc < 4; ++pc) {
            __syncthreads();
            if ((w & 1) == (pc >> 1)) {
                int tjb = (pc & 1) * 2;
#pragma unroll
                for (int ti = 0; ti < MT; ++ti)
#pragma unroll
                    for (int tj2 = 0; tj2 < 2; ++tj2)
#pragma unroll
                        for (int r = 0; r < 4; ++r) {
                            int tj = tjb + tj2;
                            int row = mwoff + ti * 16 + lq * 4 + r;
                            int cl = tj2 * 16 + lr;                    // 0..31
                            float v = acc[ti][tj][r] + p.bias[nbase + pc * 32 + cl];
                            eb[cl * 136 + row] = f2bb(v);
                        }
            }
            __syncthreads();
            if (nbase < 1024) {
#pragma unroll
                for (int i = 0; i < 2; ++i) {
                    int dl = (tid >> 4) + 16 * i;                      // 0..31
                    int ch = tid & 15;                                 // 8-n chunk
                    short8 d = *(short8*)&eb[dl * 136 + ch * 8];
                    int cg = nbase + pc * 32 + dl;
                    int sect = cg >> 9, hh = (cg >> 6) & 7, dd = cg & 63;
                    size_t addr = ((size_t)(sect * 256 + b * 8 + hh) * 64 + dd) * 256 + n0 + ch * 8;
                    *(short8*)&p.outB[addr] = d;
                }
            } else {
                int cv = nbase + pc * 32 - 1024;   // V channel base (mult of 32)
                int bh2 = b * 8 + (cv >> 6);
                int d0 = cv & 63;                  // 0 or 32
#pragma unroll
                for (int i = 0; i < 2; ++i) {
                    int idx = i * 256 + tid;       // 0..511
                    int n = idx >> 2, oc = idx & 3;
                    ushort8 dv;
#pragma unroll
                    for (int j = 0; j < 8; ++j) dv[j] = eb[(oc * 8 + j) * 136 + n];
                    *(ushort8*)&p.outB[(size_t)8388608 + (size_t)bh2 * 16384 +
                                       (size_t)(n0 + n) * 64 + d0 + oc * 8] = dv;
                }
            }
        }
    } else if constexpr (MODE == 2) {
        // convT pixel scatter -> eb [256 pix][40 us], 64B/pixel stores.
        ushort* eb = (ushort*)smem;
        ushort* ybase = (mbase < 2048) ? p.outB : (p.outB2 - (size_t)8192 * 512);
        int obase = nbase >> 2;
#pragma unroll
        for (int hf = 0; hf < 2; ++hf) {
            __syncthreads();
            if ((w >> 1) == hf) {
#pragma unroll
                for (int ti = 0; ti < MT; ++ti)
#pragma unroll
                    for (int tj = 0; tj < NT; ++tj)
#pragma unroll
                        for (int r = 0; r < 4; ++r) {
                            int rl = (mwoff - hf * 64) + ti * 16 + lq * 4 + r; // 0..63
                            int cgl = nwoff + tj * 16 + lr;                    // 0..127
                            int o_l = cgl >> 2, pp = (cgl >> 1) & 1, qq = cgl & 1;
                            int pix = ((rl >> 4) * 2 + pp) * 32 + (rl & 15) * 2 + qq;
                            float v = acc[ti][tj][r] + p.bias[obase + o_l];
                            eb[pix * 40 + o_l] = f2bb(v);
                        }
            }
            __syncthreads();
            int hhbase = ((mbase & 255) >> 4) + hf * 4;
            int prb = (mbase >> 8) * 32 + 2 * hhbase;
#pragma unroll
            for (int i = 0; i < 4; ++i) {
                int pix = i * 64 + (tid >> 2);
                int ch = tid & 3;
                short8 d = *(short8*)&eb[pix * 40 + ch * 8];
                int pr = (prb + (pix >> 5)) * 32 + (pix & 31);
                *(short8*)&ybase[(size_t)pr * 512 + obase + ch * 8] = d;
            }
        }
    }
}

// ---------------------------------------------------------------------------
// r7: fused MLP v2. 512 blocks x 512 thr, 64 y-rows/block, 2 blocks/CU.
// d_out = inp + gelu(y @ W1^T + b1) @ W2^T + b2.
// LDS 80KB: Asm [64][512] (64KB, chunk-XOR swz) + Hsm [64][128] (16KB, swz).
// Hidden loop: 16 chunks of 128:
//   GEMM1 SWAPPED: acc1[mt] = mfma(W1frag, yfrag) -> C^T: lane holds 4
//   consecutive h at fixed m -> gelu+bias -> ONE ushort4 (8B) Hsm store.
//   GEMM2: acc2[mt][nt] += mfma(Hfrag, W2frag), K=128 (4 ksteps).
// W frags register-direct from L2 (W1+W2 = 4MB, L2-resident).
// Epilogue: fp32 float4 read-add-write vs inp.
// ---------------------------------------------------------------------------
__global__ __launch_bounds__(512, 4) void mlp_fused_k(
    const ushort* __restrict__ yB, const ushort* __restrict__ yT,
    const ushort* __restrict__ w1, const ushort* __restrict__ w2,
    const float* __restrict__ b1, const float* __restrict__ b2,
    const float* __restrict__ inp, float* __restrict__ outF) {
    __shared__ __align__(16) ushort Asm[64 * 512];   // 64 KiB
    __shared__ __align__(16) ushort Hsm[64 * 128];   // 16 KiB
    int tid = threadIdx.x;
    int lane = tid & 63, w = tid >> 6;               // 8 waves
    int lr = lane & 15, lq = lane >> 4;
    // XCD-band swizzle over 512 blocks (512 % 8 == 0, bijective)
    int wgid = blockIdx.x;
    int swz = (wgid & 7) * 64 + (wgid >> 3);
    int mbase = swz * 64;
    const ushort* yb = (mbase < 8192) ? (yB + (size_t)mbase * 512)
                                      : (yT + (size_t)(mbase - 8192) * 512);
    // stage A: one full 1KiB row per gl2lds instr; lane l -> phys chunk l,
    // source chunk l^(row&7) -> LDS holds swizzled layout with linear dest.
#pragma unroll
    for (int j = 0; j < 8; ++j) {
        int row = w * 8 + j;
        int sc = lane ^ (row & 7);
        gl2lds16(yb + (size_t)row * 512 + sc * 8, &Asm[row * 512]);
    }
    int ocol0 = w * 64;          // GEMM2 wave out-col strip
    int hcol0 = w * 16;          // GEMM1 wave h-col strip (within 128-chunk)
    float b2v[4];
#pragma unroll
    for (int nt = 0; nt < 4; ++nt) b2v[nt] = b2[ocol0 + nt * 16 + lr];
    asm volatile("s_waitcnt vmcnt(0)" ::: "memory");
    __syncthreads();

    f32x4 acc2[4][4] = {};
#pragma unroll 1
    for (int hb = 0; hb < 16; ++hb) {
        // ---- GEMM1 (swapped): C^T[h][m]; wave h-strip = 16, K=512 ----
        f32x4 acc1[4] = {};
#pragma unroll
        for (int kh = 0; kh < 16; ++kh) {
            short8 bf1 = *(const short8*)&w1[(size_t)(hb * 128 + hcol0 + lr) * 512 + kh * 32 + lq * 8];
#pragma unroll
            for (int mt = 0; mt < 4; ++mt) {
                int row = mt * 16 + lr;
                int c = kh * 4 + lq;
                short8 af = *(const short8*)&Asm[row * 512 + ((c ^ (row & 7)) << 3)];
                acc1[mt] = __builtin_amdgcn_mfma_f32_16x16x32_bf16(bf1, af, acc1[mt], 0, 0, 0);
            }
        }
        // ---- gelu + pack: lane holds h0..h0+3 at fixed m -> 8B store ----
        __syncthreads();   // WAR: all GEMM2 reads of previous hb complete
        int h0 = hcol0 + lq * 4;
        float4 b1v = *(const float4*)&b1[hb * 128 + h0];
#pragma unroll
        for (int mt = 0; mt < 4; ++mt) {
            int m = mt * 16 + lr;
            ushort4v hv;
#pragma unroll
            for (int r = 0; r < 4; ++r) {
                float v = acc1[mt][r] + ((const float*)&b1v)[r];
                v = 0.5f * v * (1.0f + erff(v * 0.70710678118654752f));
                hv[r] = f2bb(v);
            }
            int phys = (h0 >> 3) ^ (m & 7);
            *(ushort4v*)&Hsm[m * 128 + (phys << 3) + (h0 & 7)] = hv;
        }
        __syncthreads();
        // ---- GEMM2: acc2 += Hsm x W2 (register-direct B), K=128 ----
#pragma unroll
        for (int kh = 0; kh < 4; ++kh) {
            short8 bf2v[4];
#pragma unroll
            for (int nt = 0; nt < 4; ++nt)
                bf2v[nt] = *(const short8*)&w2[(size_t)(ocol0 + nt * 16 + lr) * 2048 + hb * 128 + kh * 32 + lq * 8];
#pragma unroll
            for (int mt = 0; mt < 4; ++mt) {
                int row = mt * 16 + lr;
                int c = kh * 4 + lq;
                short8 ha = *(const short8*)&Hsm[row * 128 + ((c ^ (row & 7)) << 3)];
#pragma unroll
                for (int nt = 0; nt < 4; ++nt)
                    acc2[mt][nt] = __builtin_amdgcn_mfma_f32_16x16x32_bf16(ha, bf2v[nt], acc2[mt][nt], 0, 0, 0);
            }
        }
    }
    // ---- epilogue: d_out[b][col][hw] = inp + acc2 + b2; hw contig per lane ----
    int b = mbase >> 10;
    int hwb = mbase & 1023;
#pragma unroll
    for (int mt = 0; mt < 4; ++mt) {
#pragma unroll
        for (int nt = 0; nt < 4; ++nt) {
            int col = ocol0 + nt * 16 + lr;
            size_t idx = ((size_t)(b * 512 + col)) * 1024 + hwb + mt * 16 + lq * 4;
            float4 xin = *(const float4*)&inp[idx];
            float4 o4;
            o4.x = xin.x + acc2[mt][nt][0] + b2v[nt];
            o4.y = xin.y + acc2[mt][nt][1] + b2v[nt];
            o4.z = xin.z + acc2[mt][nt][2] + b2v[nt];
            o4.w = xin.w + acc2[mt][nt][3] + b2v[nt];
            *(float4*)&outF[idx] = o4;
        }
    }
}

// ---------------------------------------------------------------------------
// K5: cosine attention per (b,h), MFMA. qkvp: Q,K [sect][bh][64 d][256 n];
// V transposed [bh][256 n][64 d]. Out attn_o [b*256+n][h*64+d] bf16.
// ---------------------------------------------------------------------------
__global__ __launch_bounds__(256) void attn_k(const ushort* __restrict__ qkvp,
                                              const float* __restrict__ mask_u,
                                              const float* __restrict__ temp,
                                              ushort* __restrict__ attn_out) {
    __shared__ float Sb[64 * 65];          // scores f32
    __shared__ ushort Pb[64 * 64];         // probs bf16, chunk^(row&7) swizzle
    __shared__ float fq[64], fk[64];
    int tid = threadIdx.x;
    int bh = blockIdx.x;
    int b = bh >> 3, h = bh & 7;
    const ushort* q  = qkvp + (size_t)bh * 16384;
    const ushort* k  = qkvp + 4194304 + (size_t)bh * 16384;
    const ushort* vt = qkvp + 8388608 + (size_t)bh * 16384;   // [256 n][64 d]
    int lane = tid & 63, w = tid >> 6;
    int lr = lane & 15, lq = lane >> 4;

    // ---- norms: 4 threads per row, 64 elems each ----
    {
        int row = tid >> 2, qd = tid & 3;
        const ushort* qr = q + row * 256 + qd * 64;
        const ushort* kr = k + row * 256 + qd * 64;
        float s = 0.f, t = 0.f;
#pragma unroll
        for (int i = 0; i < 8; ++i) {
            short8 a8 = *(const short8*)&qr[i * 8];
            short8 b8 = *(const short8*)&kr[i * 8];
#pragma unroll
            for (int j = 0; j < 8; ++j) {
                float fa = bf2f((ushort)a8[j]); s += fa * fa;
                float fb = bf2f((ushort)b8[j]); t += fb * fb;
            }
        }
        s += __shfl_xor(s, 1); s += __shfl_xor(s, 2);
        t += __shfl_xor(t, 1); t += __shfl_xor(t, 2);
        if (qd == 0) {
            fq[row] = 1.0f / fmaxf(sqrtf(s), 1e-12f);
            fk[row] = 1.0f / fmaxf(sqrtf(t), 1e-12f);
        }
    }
    __syncthreads();

    // ---- QK^T: 64x64, K=256. Wave quadrants 32x32 (2x2 tiles x 8 ksteps) ----
    int mq = (w >> 1) * 32, nq = (w & 1) * 32;
    f32x4 acc[2][2] = {};
    for (int kb = 0; kb < 256; kb += 32) {
        short8 af[2], bfr[2];
#pragma unroll
        for (int ti = 0; ti < 2; ++ti)
            af[ti] = *(const short8*)&q[(mq + ti * 16 + lr) * 256 + kb + lq * 8];
#pragma unroll
        for (int tj = 0; tj < 2; ++tj)
            bfr[tj] = *(const short8*)&k[(nq + tj * 16 + lr) * 256 + kb + lq * 8];
#pragma unroll
        for (int i = 0; i < 2; ++i)
#pragma unroll
            for (int j = 0; j < 2; ++j)
                acc[i][j] = __builtin_amdgcn_mfma_f32_16x16x32_bf16(af[i], bfr[j], acc[i][j], 0, 0, 0);
    }

    // ---- scale, mask, write S to LDS ----
    float tv = temp[h];
#pragma unroll
    for (int i = 0; i < 2; ++i)
#pragma unroll
        for (int r = 0; r < 4; ++r) {
            int d = mq + i * 16 + lq * 4 + r;
#pragma unroll
            for (int j = 0; j < 2; ++j) {
                int e = nq + j * 16 + lr;
                float sc = acc[i][j][r] * fq[d] * fk[e] * tv;
                float mu = mask_u[((size_t)bh * 64 + d) * 64 + e];
                if (mu < 0.2f) sc -= 1e12f;
                Sb[d * 65 + e] = sc;
            }
        }
    __syncthreads();

    // ---- softmax rows + pack P -> bf16 swizzled Pb ----
    {
        int row = tid >> 2, sub = tid & 3;
        float ev[16];
        float mx = -INFINITY;
#pragma unroll
        for (int i = 0; i < 16; ++i) { float s = Sb[row * 65 + sub * 16 + i]; ev[i] = s; mx = fmaxf(mx, s); }
        mx = fmaxf(mx, __shfl_xor(mx, 1));
        mx = fmaxf(mx, __shfl_xor(mx, 2));
        float sum = 0.f;
#pragma unroll
        for (int i = 0; i < 16; ++i) { ev[i] = expf(ev[i] - mx); sum += ev[i]; }
        sum += __shfl_xor(sum, 1);
        sum += __shfl_xor(sum, 2);
        float inv = 1.0f / sum;
        unsigned int* Pb32 = (unsigned int*)Pb;
#pragma unroll
        for (int kk = 0; kk < 8; ++kk) {
            unsigned int lo = f2bb(ev[2 * kk] * inv);
            unsigned int hi = f2bb(ev[2 * kk + 1] * inv);
            int c8 = sub * 2 + (kk >> 2);
            int ph = c8 ^ (row & 7);
            Pb32[row * 32 + ph * 4 + (kk & 3)] = (hi << 16) | lo;
        }
    }
    __syncthreads();

    // ---- PV: O[64 d][256 n] = P[64][64] * Vt[n][e]. Wave owns 64-n strip ----
    int nw = w * 64;
    f32x4 o[4][4] = {};
#pragma unroll
    for (int ks = 0; ks < 2; ++ks) {
        short8 pa[4];
#pragma unroll
        for (int mt = 0; mt < 4; ++mt) {
            int d = mt * 16 + lr;
            int ph = (ks * 4 + lq) ^ (d & 7);
            pa[mt] = *(const short8*)&Pb[d * 64 + ph * 8];
        }
#pragma unroll
        for (int nt = 0; nt < 4; ++nt) {
            short8 vb = *(const short8*)&vt[(size_t)(nw + nt * 16 + lr) * 64 + ks * 32 + lq * 8];
#pragma unroll
            for (int mt = 0; mt < 4; ++mt)
                o[mt][nt] = __builtin_amdgcn_mfma_f32_16x16x32_bf16(pa[mt], vb, o[mt][nt], 0, 0, 0);
        }
    }

    // ---- store O: attn_o[b*256+n][h*64+d], 8B packed per (mt,nt) ----
#pragma unroll
    for (int mt = 0; mt < 4; ++mt) {
        int d0 = mt * 16 + lq * 4;
#pragma unroll
        for (int nt = 0; nt < 4; ++nt) {
            int n = nw + nt * 16 + lr;
            ushort4v ov;
#pragma unroll
            for (int r = 0; r < 4; ++r) ov[r] = f2bb(o[mt][nt][r]);
            *(ushort4v*)&attn_out[((size_t)(b * 256 + n)) * 512 + h * 64 + d0] = ov;
        }
    }
}

// ---------------------------------------------------------------------------
extern "C" void kernel_launch(void* const* d_in, const int* in_sizes, int n_in,
                              void* d_out, int out_size, void* d_ws, size_t ws_size,
                              hipStream_t stream) {
    const float* x      = (const float*)d_in[0];
    const float* mask_u = (const float*)d_in[1];
    const float* dw_w   = (const float*)d_in[2];
    const float* dw_b   = (const float*)d_in[3];
    const float* ln1_g  = (const float*)d_in[4];
    const float* ln1_b  = (const float*)d_in[5];
    const float* qkv_w  = (const float*)d_in[6];
    const float* qkv_b  = (const float*)d_in[7];
    const float* temp   = (const float*)d_in[8];
    const float* proj_w = (const float*)d_in[9];
    const float* proj_b = (const float*)d_in[10];
    const float* ct_w   = (const float*)d_in[11];
    const float* ct_b   = (const float*)d_in[12];
    const float* ln2_g  = (const float*)d_in[13];
    const float* ln2_b  = (const float*)d_in[14];
    const float* pw1_w  = (const float*)d_in[15];
    const float* pw1_b  = (const float*)d_in[16];
    const float* pw2_w  = (const float*)d_in[17];
    const float* pw2_b  = (const float*)d_in[18];

    char* wsb = (char*)d_ws;
    float* mean1 = (float*)wsb;
    float* rstd1 = mean1 + 8192;
    ushort* wq = (ushort*)(wsb + 524288);
    ushort* wp = wq + 786432;
    ushort* wc = wp + 262144;
    ushort* w1 = wc + 1048576;
    ushort* w2 = w1 + 1048576;
    ushort* xp     = (ushort*)(wsb + 8912896);   // region A: 8 MiB
    ushort* t2     = xp;                         // A reuse
    ushort* a_ln   = (ushort*)(wsb + 17301504);  // region Br: 8 MiB
    ushort* yB     = a_ln;                       // Br reuse: y0 rows 0..8191
    ushort* qkvp   = (ushort*)(wsb + 25690112);  // region CD: 24 MiB
    ushort* attn_o = (ushort*)(wsb + 50855936);  // CD tail: 8 MiB
    ushort* yT     = (ushort*)(wsb + 59244544);  // region T: 24 MiB

    // 0. weight conversions
    cvtw_k<<<768,  256, 0, stream>>>(qkv_w,  wq, 196608);
    cvtw_k<<<256,  256, 0, stream>>>(proj_w, wp, 65536);
    cvtw_k<<<1024, 256, 0, stream>>>(pw1_w,  w1, 262144);
    cvtw_k<<<1024, 256, 0, stream>>>(pw2_w,  w2, 262144);
    cvtt_k<<<dim3(64, 16), 256, 0, stream>>>(ct_w, wc);
    // 1. depthwise conv + residual + avgpool
    dwpool_k<<<32 * 512, 256, 0, stream>>>(x, dw_w, dw_b, xp);
    // 2-3. LN1 stats + apply/transpose -> a_ln
    ln1_stats_k<<<128, 256, 0, stream>>>(xp, mean1, rstd1);
    ln1_apply_k<<<1024, 256, 0, stream>>>(xp, mean1, rstd1, ln1_g, ln1_b, a_ln);
    // 4. QKV gemm -> qkvp (Q/K permuted, V transposed)
    {
        GP p{}; p.A = a_ln; p.W = wq; p.bias = qkv_b; p.outB = qkvp; p.K = 512;
        mgemm_k<0, 128><<<dim3(12, 64), 256, 0, stream>>>(p);
    }
    // 5. attention (MFMA)
    attn_k<<<256, 256, 0, stream>>>(qkvp, mask_u, temp, attn_o);
    // 6. proj gemm (x2) -> t2
    {
        GP p{}; p.A = attn_o; p.W = wp; p.bias = proj_b; p.outB = t2; p.K = 512;
        mgemm_k<1, 128><<<dim3(4, 64), 256, 0, stream>>>(p);
    }
    // 7. convT gemm -> y0 (split yB/yT), channels-last
    {
        GP p{}; p.A = t2; p.W = wc; p.bias = ct_b;
        p.outB = yB; p.outB2 = yT; p.K = 512;
        mgemm_k<2, 128><<<dim3(16, 64), 256, 0, stream>>>(p);
    }
    // 8. LN2 fused stats+normalize in place
    ln2_fuse_k<<<8192, 256, 0, stream>>>(yB, yT, ln2_g, ln2_b);
    // 9. fused MLP: one dispatch, whole 32768 rows
    mlp_fused_k<<<512, 512, 0, stream>>>(yB, yT, w1, w2, pw1_b, pw2_b,
                                         x, (float*)d_out);
}